// Round 1
// baseline (138.735 us; speedup 1.0000x reference)
//
#include <hip/hip_runtime.h>
#include <hip/hip_bf16.h>

#define BT    8192      // B*T tokens (4*2048)
#define SEQ_T 2048
#define DIN   1024
#define NH    16
#define NK    8
#define DH    64
#define DO    64
#define TT    128       // tokens per block in moe kernel

typedef __bf16 bf16;
typedef __attribute__((ext_vector_type(8))) __bf16 bf16x8;
typedef __attribute__((ext_vector_type(4))) float floatx4;

// ---------------------------------------------------------------------------
// Kernel 1: (a) scores_t[k][token] = phi[t,k] + x[token,:]·diag[k,:]  (fp32)
//           (b) wt[h][k][o][i] = bf16(W[h][k][i][o])   (i-contiguous for MFMA)
// ---------------------------------------------------------------------------
__global__ __launch_bounds__(256) void prep_kernel(
    const float* __restrict__ x, const float* __restrict__ weight,
    const float* __restrict__ diag, const float* __restrict__ phi,
    float* __restrict__ scores_t, bf16* __restrict__ wt)
{
  int blk = blockIdx.x, tid = threadIdx.x;
  if (blk < BT / 4) {
    // one wave per token
    int wave = tid >> 6, lane = tid & 63;
    int token = blk * 4 + wave;
    const float* xr = x + (size_t)token * DIN;
    float acc[NK];
#pragma unroll
    for (int k = 0; k < NK; k++) acc[k] = 0.f;
#pragma unroll
    for (int j = 0; j < DIN / 64; j++) {
      float xv = xr[lane + 64 * j];
#pragma unroll
      for (int k = 0; k < NK; k++)
        acc[k] = fmaf(xv, diag[k * DIN + lane + 64 * j], acc[k]);
    }
    // 64-lane butterfly reduction for each of the 8 partial sums
#pragma unroll
    for (int k = 0; k < NK; k++) {
      float v = acc[k];
#pragma unroll
      for (int off = 32; off >= 1; off >>= 1) v += __shfl_xor(v, off, 64);
      acc[k] = v;
    }
    if (lane == 0) {
      int t = token & (SEQ_T - 1);
#pragma unroll
      for (int k = 0; k < NK; k++)
        scores_t[(size_t)k * BT + token] = phi[t * NK + k] + acc[k];
    }
  } else {
    // weight transpose+convert: 524288 elements over 128 blocks * 256 thr * 16
    int base = (blk - BT / 4) * 256 + tid;
#pragma unroll
    for (int j = 0; j < 16; j++) {
      int e = base + 32768 * j;          // e = ((hk*64 + o)*64 + i)
      int i = e & 63, o = (e >> 6) & 63, hk = e >> 12;
      wt[e] = (bf16)weight[((size_t)hk * DH + i) * DO + o];
    }
  }
}

// ---------------------------------------------------------------------------
// Kernel 2: per block = (head h, 128-token tile). 8 waves, each owns a
// 32x32 output tile. For each expert k: z = x_h @ W[h,k] via
// mfma_f32_16x16x32_bf16, then y += scores[:,k] * z  (fp32).
// LDS-free: weights/scores served from L1/L2 (1 MiB bf16 weights resident).
// ---------------------------------------------------------------------------
__global__ __launch_bounds__(512) void moe_kernel(
    const float* __restrict__ x, const bf16* __restrict__ wt,
    const float* __restrict__ scores_t, float* __restrict__ out)
{
  // group blocks by head for L2 locality: h = blockIdx>>6
  int h  = blockIdx.x >> 6;
  int t0 = (blockIdx.x & 63) * TT;
  int tid  = threadIdx.x;
  int lane = tid & 63;
  int w    = tid >> 6;          // 8 waves
  int R0 = (w >> 1) * 32;       // wave row base within tile (4 row groups)
  int C0 = (w & 1)  * 32;       // wave col base (2 col groups)
  int l15 = lane & 15, q = lane >> 4;

  // ---- A fragments (x slice, expert-independent): A[m=lane&15][i=q*8+j] ----
  bf16x8 a[2][2];
#pragma unroll
  for (int rb = 0; rb < 2; rb++) {
    int arow = t0 + R0 + rb * 16 + l15;
    const float* ap = x + (size_t)arow * DIN + h * DH;
#pragma unroll
    for (int ki = 0; ki < 2; ki++) {
      const floatx4* p = (const floatx4*)(ap + ki * 32 + q * 8);
      floatx4 f0 = p[0], f1 = p[1];
      bf16x8 av;
      av[0] = (bf16)f0[0]; av[1] = (bf16)f0[1];
      av[2] = (bf16)f0[2]; av[3] = (bf16)f0[3];
      av[4] = (bf16)f1[0]; av[5] = (bf16)f1[1];
      av[6] = (bf16)f1[2]; av[7] = (bf16)f1[3];
      a[rb][ki] = av;
    }
  }

  floatx4 y[2][2];
#pragma unroll
  for (int rb = 0; rb < 2; rb++)
#pragma unroll
    for (int nb = 0; nb < 2; nb++)
      y[rb][nb] = (floatx4){0.f, 0.f, 0.f, 0.f};

  const bf16* wh = wt + (size_t)h * NK * DO * DH;

#pragma unroll
  for (int k = 0; k < NK; k++) {
    // B fragments: B[i=q*8+j][o=lane&15] from wt[h][k][o][i] (i-contiguous)
    bf16x8 b[2][2];
#pragma unroll
    for (int nb = 0; nb < 2; nb++) {
      const bf16* bp = wh + ((size_t)k * DO + C0 + nb * 16 + l15) * DH + q * 8;
      b[nb][0] = *(const bf16x8*)bp;
      b[nb][1] = *(const bf16x8*)(bp + 32);
    }
    // scores for this expert: rows R0+rb*16+q*4 .. +3 (contiguous -> float4)
    floatx4 s4[2];
#pragma unroll
    for (int rb = 0; rb < 2; rb++)
      s4[rb] = *(const floatx4*)(scores_t + (size_t)k * BT + t0 + R0 + rb * 16 + q * 4);

#pragma unroll
    for (int rb = 0; rb < 2; rb++)
#pragma unroll
      for (int nb = 0; nb < 2; nb++) {
        floatx4 z = {0.f, 0.f, 0.f, 0.f};
        z = __builtin_amdgcn_mfma_f32_16x16x32_bf16(a[rb][0], b[nb][0], z, 0, 0, 0);
        z = __builtin_amdgcn_mfma_f32_16x16x32_bf16(a[rb][1], b[nb][1], z, 0, 0, 0);
#pragma unroll
        for (int r = 0; r < 4; r++)
          y[rb][nb][r] += s4[rb][r] * z[r];
      }
  }

  // ---- store: C/D layout col=lane&15, row=q*4+r ----
#pragma unroll
  for (int rb = 0; rb < 2; rb++)
#pragma unroll
    for (int nb = 0; nb < 2; nb++) {
      int row = t0 + R0 + rb * 16 + q * 4;
      float* op = out + (size_t)row * (NH * DO) + h * DO + C0 + nb * 16 + l15;
#pragma unroll
      for (int r = 0; r < 4; r++)
        op[(size_t)r * (NH * DO)] = y[rb][nb][r];
    }
}

extern "C" void kernel_launch(void* const* d_in, const int* in_sizes, int n_in,
                              void* d_out, int out_size, void* d_ws, size_t ws_size,
                              hipStream_t stream) {
  const float* x      = (const float*)d_in[0];
  const float* weight = (const float*)d_in[1];
  const float* diag   = (const float*)d_in[2];
  const float* phi    = (const float*)d_in[3];
  float* out = (float*)d_out;

  // workspace layout: [0, 1MiB) bf16 transposed weights; [1MiB, 1.25MiB) scores_t
  bf16*  wt       = (bf16*)d_ws;
  float* scores_t = (float*)((char*)d_ws + (size_t)NH * NK * DH * DO * 2);

  // 2048 score blocks (4 tokens each) + 128 weight-transpose blocks
  prep_kernel<<<BT / 4 + 128, 256, 0, stream>>>(x, weight, diag, phi, scores_t, wt);
  // 16 heads * 64 token-tiles
  moe_kernel<<<NH * (BT / TT), 512, 0, stream>>>(x, wt, scores_t, out);
}

// Round 2
// 110.630 us; speedup vs baseline: 1.2541x; 1.2541x over previous
//
#include <hip/hip_runtime.h>
#include <hip/hip_bf16.h>

#define BT    8192      // B*T tokens (4*2048)
#define SEQ_T 2048
#define DIN   1024
#define NH    16
#define NK    8
#define DH    64
#define DO    64
#define TT    256       // tokens per block in moe kernel

typedef __bf16 bf16;
typedef __attribute__((ext_vector_type(8))) __bf16 bf16x8;
typedef __attribute__((ext_vector_type(4))) __bf16 bf16x4;
typedef __attribute__((ext_vector_type(4))) float floatx4;

__device__ inline void async_load16(const void* g, void* l) {
  __builtin_amdgcn_global_load_lds(
      (const __attribute__((address_space(1))) unsigned int*)g,
      (__attribute__((address_space(3))) unsigned int*)l, 16, 0, 0);
}

// ---------------------------------------------------------------------------
// Kernel 1: (a) scores_t[k][token] = phi[t,k] + x[token,:]·diag[k,:]  (fp32)
//           (b) wt[h][k][o][i] = bf16(W[h][k][i][o])  via LDS transpose,
//               both global sides fully coalesced.
// ---------------------------------------------------------------------------
__global__ __launch_bounds__(256) void prep_kernel(
    const float* __restrict__ x, const float* __restrict__ weight,
    const float* __restrict__ diag, const float* __restrict__ phi,
    float* __restrict__ scores_t, bf16* __restrict__ wt)
{
  int blk = blockIdx.x, tid = threadIdx.x;
  if (blk < BT / 4) {
    // ---- scores: one wave per token, float4 loads ----
    int wave = tid >> 6, lane = tid & 63;
    int token = blk * 4 + wave;
    const floatx4* xr = (const floatx4*)(x + (size_t)token * DIN);
    const floatx4* dg = (const floatx4*)diag;
    floatx4 acc[NK];
#pragma unroll
    for (int k = 0; k < NK; k++) acc[k] = (floatx4){0.f, 0.f, 0.f, 0.f};
#pragma unroll
    for (int it = 0; it < 4; it++) {
      floatx4 xv = xr[it * 64 + lane];
#pragma unroll
      for (int k = 0; k < NK; k++) {
        floatx4 dv = dg[k * 256 + it * 64 + lane];
        acc[k] += xv * dv;
      }
    }
    float r[NK];
#pragma unroll
    for (int k = 0; k < NK; k++)
      r[k] = (acc[k][0] + acc[k][1]) + (acc[k][2] + acc[k][3]);
#pragma unroll
    for (int k = 0; k < NK; k++) {
      float v = r[k];
#pragma unroll
      for (int off = 32; off >= 1; off >>= 1) v += __shfl_xor(v, off, 64);
      r[k] = v;
    }
    if (lane == 0) {
      int t = token & (SEQ_T - 1);
#pragma unroll
      for (int k = 0; k < NK; k++)
        scores_t[(size_t)k * BT + token] = phi[t * NK + k] + r[k];
    }
  } else {
    // ---- weight transpose: one (h,k) 64x64 tile per block ----
    __shared__ bf16 tile[64 * 68];   // stride 68 keeps bf16x4 reads 8B-aligned
    int hk = blk - BT / 4;           // 0..127
    const float* wsrc = weight + (size_t)hk * DH * DO;
#pragma unroll
    for (int it = 0; it < 4; it++) {
      int idx = it * 1024 + tid * 4;
      int i = idx >> 6, o = idx & 63;          // read W[hk][i][o..o+3] coalesced
      floatx4 v = *(const floatx4*)(wsrc + idx);
#pragma unroll
      for (int r = 0; r < 4; r++)
        tile[(o + r) * 68 + i] = (bf16)v[r];
    }
    __syncthreads();
#pragma unroll
    for (int it = 0; it < 4; it++) {
      int idx = it * 1024 + tid * 4;
      int o2 = idx >> 6, i2 = idx & 63;        // write wt[hk][o2][i2..i2+3] coalesced
      bf16x4 v = *(const bf16x4*)&tile[o2 * 68 + i2];
      *(bf16x4*)(wt + (size_t)hk * 4096 + idx) = v;
    }
  }
}

// ---------------------------------------------------------------------------
// Kernel 2: block = (head h, 256-token tile), 8 waves. Head weights (64 KiB
// bf16) staged in LDS via global_load_lds w=16 with a rotation swizzle on
// 16B chunks (phys_chunk = (logical_chunk + row) & 7) so B-fragment
// ds_read_b128 is bank-uniform. Scores staged in LDS too. Each wave owns a
// 64x32 output tile: per expert 16 MFMAs fed by 4 ds_read_b128.
// ---------------------------------------------------------------------------
__global__ __launch_bounds__(512, 4) void moe_kernel(
    const float* __restrict__ x, const bf16* __restrict__ wt,
    const float* __restrict__ scores_t, float* __restrict__ out)
{
  __shared__ char smem[NK * DO * DH * 2 + NK * TT * 4];   // 64 KiB + 8 KiB
  bf16*  w_lds = (bf16*)smem;
  float* s_lds = (float*)(smem + NK * DO * DH * 2);

  int h  = blockIdx.x >> 5;
  int t0 = (blockIdx.x & 31) * TT;
  int tid = threadIdx.x, lane = tid & 63, w = tid >> 6;
  int l15 = lane & 15, q = lane >> 4;
  int R0 = (w >> 1) * 64;       // wave row base (4 row groups of 64)
  int C0 = (w & 1) * 32;        // wave col base (2 col groups of 32)

  // ---- stage weights: 4096 16B-chunks, swizzled on the global side ----
  const bf16* wh = wt + (size_t)h * NK * DO * DH;
#pragma unroll
  for (int it = 0; it < 8; it++) {
    int L = it * 512 + tid;            // physical chunk index in LDS
    int row = L >> 3, pc = L & 7;      // row = k*64 + o
    int lc = (pc - row) & 7;           // logical (global) chunk in this row
    async_load16(wh + row * 64 + lc * 8,
                 (char*)w_lds + it * 8192 + w * 1024);   // wave-uniform base
  }

  // ---- stage scores: 8 experts x 256 tokens (fp32) ----
  {
    int k = tid >> 6, t4 = (tid & 63) * 4;
    floatx4 sv = *(const floatx4*)(scores_t + (size_t)k * BT + t0 + t4);
    *(floatx4*)(s_lds + k * TT + t4) = sv;
  }

  // ---- A fragments (x slice, expert-independent) ----
  bf16x8 a[4][2];
#pragma unroll
  for (int rb = 0; rb < 4; rb++) {
    int arow = t0 + R0 + rb * 16 + l15;
    const float* ap = x + (size_t)arow * DIN + h * DH;
#pragma unroll
    for (int ki = 0; ki < 2; ki++) {
      const floatx4* p = (const floatx4*)(ap + ki * 32 + q * 8);
      floatx4 f0 = p[0], f1 = p[1];
      bf16x8 av;
      av[0] = (bf16)f0[0]; av[1] = (bf16)f0[1];
      av[2] = (bf16)f0[2]; av[3] = (bf16)f0[3];
      av[4] = (bf16)f1[0]; av[5] = (bf16)f1[1];
      av[6] = (bf16)f1[2]; av[7] = (bf16)f1[3];
      a[rb][ki] = av;
    }
  }

  floatx4 y[4][2];
#pragma unroll
  for (int rb = 0; rb < 4; rb++)
#pragma unroll
    for (int nb = 0; nb < 2; nb++)
      y[rb][nb] = (floatx4){0.f, 0.f, 0.f, 0.f};

  __syncthreads();

#pragma unroll
  for (int k = 0; k < NK; k++) {
    bf16x8 b[2][2];
#pragma unroll
    for (int nb = 0; nb < 2; nb++) {
      int o = C0 + nb * 16 + l15;
      int row = k * 64 + o;
#pragma unroll
      for (int ki = 0; ki < 2; ki++) {
        int pc = (ki * 4 + q + o) & 7;                 // rotation swizzle
        b[nb][ki] = *(const bf16x8*)(w_lds + row * 64 + pc * 8);
      }
    }
    floatx4 s4[4];
#pragma unroll
    for (int rb = 0; rb < 4; rb++)
      s4[rb] = *(const floatx4*)(s_lds + k * TT + R0 + rb * 16 + q * 4);

#pragma unroll
    for (int rb = 0; rb < 4; rb++)
#pragma unroll
      for (int nb = 0; nb < 2; nb++) {
        floatx4 z = {0.f, 0.f, 0.f, 0.f};
        z = __builtin_amdgcn_mfma_f32_16x16x32_bf16(a[rb][0], b[nb][0], z, 0, 0, 0);
        z = __builtin_amdgcn_mfma_f32_16x16x32_bf16(a[rb][1], b[nb][1], z, 0, 0, 0);
#pragma unroll
        for (int r = 0; r < 4; r++)
          y[rb][nb][r] += s4[rb][r] * z[r];
      }
  }

  // ---- store: C/D layout col=lane&15, row=q*4+r ----
#pragma unroll
  for (int rb = 0; rb < 4; rb++)
#pragma unroll
    for (int nb = 0; nb < 2; nb++) {
      int row = t0 + R0 + rb * 16 + q * 4;
      float* op = out + (size_t)row * (NH * DO) + h * DO + C0 + nb * 16 + l15;
#pragma unroll
      for (int r = 0; r < 4; r++)
        op[(size_t)r * (NH * DO)] = y[rb][nb][r];
    }
}

extern "C" void kernel_launch(void* const* d_in, const int* in_sizes, int n_in,
                              void* d_out, int out_size, void* d_ws, size_t ws_size,
                              hipStream_t stream) {
  const float* x      = (const float*)d_in[0];
  const float* weight = (const float*)d_in[1];
  const float* diag   = (const float*)d_in[2];
  const float* phi    = (const float*)d_in[3];
  float* out = (float*)d_out;

  // workspace: [0, 1MiB) bf16 transposed weights; then scores_t (256 KiB)
  bf16*  wt       = (bf16*)d_ws;
  float* scores_t = (float*)((char*)d_ws + (size_t)NH * NK * DH * DO * 2);

  prep_kernel<<<BT / 4 + NH * NK, 256, 0, stream>>>(x, weight, diag, phi, scores_t, wt);
  moe_kernel<<<NH * (BT / TT), 512, 0, stream>>>(x, wt, scores_t, out);
}